// Round 2
// baseline (514.119 us; speedup 1.0000x reference)
//
#include <hip/hip_runtime.h>
#include <hip/hip_bf16.h>

#define N_NODES 100000
#define N_EDGES 3200000
#define IN_C 128
#define HID_C 64
#define OUT_C 64

#define NBUCKET 196          // ceil(N_NODES / 512); bucket = target >> 9
#define SC_EDGES 4096        // edges per scatter block
#define SC_GRID 782          // ceil(E / SC_EDGES)
#define CAP 18432            // padded bucket capacity (mean 16384 + 16 sigma)

struct EdgeRec { int s; float v; };   // source node, raw edge weight w

typedef float f32x2 __attribute__((ext_vector_type(2)));

// staged record: 8 B. x = f32 bits of w; y = s (17 bits) | t_local<<17 (9 bits)
__device__ __forceinline__ unsigned pack_bf16(float lo, float hi) {
    unsigned short l = __hip_bfloat16_raw(__float2bfloat16(lo)).x;
    unsigned short h = __hip_bfloat16_raw(__float2bfloat16(hi)).x;
    return ((unsigned)h << 16) | l;
}
__device__ __forceinline__ float bf_lo(unsigned u) {
    union { unsigned u; float f; } c; c.u = u << 16; return c.f;
}
__device__ __forceinline__ float bf_hi(unsigned u) {
    union { unsigned u; float f; } c; c.u = u & 0xffff0000u; return c.f;
}
// unpack a bf16 pair into an f32x2 register pair (lshl + and, exact)
__device__ __forceinline__ f32x2 bfp(unsigned u) {
    union { unsigned u; float f; } lo, hi;
    lo.u = u << 16; hi.u = u & 0xffff0000u;
    f32x2 r; r.x = lo.f; r.y = hi.f; return r;
}
// packed f32 FMA: acc = a*w + acc  (v_pk_fma_f32, full-rate on gfx950)
__device__ __forceinline__ void pk_fma(f32x2& acc, f32x2 a, f32x2 w) {
    asm("v_pk_fma_f32 %0, %1, %2, %0" : "+v"(acc) : "v"(a), "v"(w));
}
// accumulate one edge's 8 channels (one uint4) with weight w
__device__ __forceinline__ void edge_acc(f32x2* acc2, uint4 u, float w) {
    f32x2 wv; wv.x = w; wv.y = w;
    pk_fma(acc2[0], bfp(u.x), wv);
    pk_fma(acc2[1], bfp(u.y), wv);
    pk_fma(acc2[2], bfp(u.z), wv);
    pk_fma(acc2[3], bfp(u.w), wv);
}

// ---- coarse scatter: edges -> padded bucket-major staging ----------------
__global__ __launch_bounds__(256) void scatter_coarse(const int* __restrict__ ei,
                                                      const float* __restrict__ ew,
                                                      int* __restrict__ gcursor,
                                                      uint2* __restrict__ tmp) {
    __shared__ int hist[256];
    __shared__ int scan[256];
    __shared__ int lcur[256];
    __shared__ int adj[256];
    __shared__ uint2 rec[SC_EDGES];           // 32 KB
    __shared__ unsigned char bk[SC_EDGES];    // 4 KB
    int tid = threadIdx.x;
    hist[tid] = 0;
    __syncthreads();
    int base = blockIdx.x * SC_EDGES;
    unsigned ys[16];
    float    ws[16];
    int      bs[16];
    for (int i = 0; i < 16; ++i) {
        int e = base + i * 256 + tid;
        if (e < N_EDGES) {
            int t = ei[N_EDGES + e];
            bs[i] = t >> 9;
            ys[i] = (unsigned)ei[e] | ((unsigned)(t & 511) << 17);
            ws[i] = ew[e];
            atomicAdd(&hist[bs[i]], 1);
        } else bs[i] = -1;
    }
    __syncthreads();
    // exclusive scan of hist
    int v = hist[tid];
    scan[tid] = v;
    __syncthreads();
    for (int off = 1; off < 256; off <<= 1) {
        int t = scan[tid];
        int add = (tid >= off) ? scan[tid - off] : 0;
        __syncthreads();
        scan[tid] = t + add;
        __syncthreads();
    }
    int excl = scan[tid] - v;
    int gb = (v > 0) ? atomicAdd(&gcursor[tid], v) : 0;
    lcur[tid] = excl;
    adj[tid] = tid * CAP + gb - excl;  // global slot for LDS slot j: adj[b]+j
    __syncthreads();
    // place edges into LDS bucket-major
    for (int i = 0; i < 16; ++i) {
        if (bs[i] >= 0) {
            int j = atomicAdd(&lcur[bs[i]], 1);
            rec[j] = make_uint2(__float_as_uint(ws[i]), ys[i]);
            bk[j] = (unsigned char)bs[i];
        }
    }
    __syncthreads();
    // run-coalesced write-out
    int count = N_EDGES - base;
    if (count > SC_EDGES) count = SC_EDGES;
    for (int j = tid; j < count; j += 256) {
        int b = bk[j];
        tmp[adj[b] + j] = rec[j];
    }
}

// ---- exclusive scan of bucket counts -> dense ed bases -------------------
__global__ __launch_bounds__(256) void bucket_scan(const int* __restrict__ gcnt,
                                                   int* __restrict__ start) {
    __shared__ int s[256];
    int tid = threadIdx.x;
    int v = gcnt[tid];
    s[tid] = v;
    __syncthreads();
    for (int off = 1; off < 256; off <<= 1) {
        int t = s[tid];
        int add = (tid >= off) ? s[tid - off] : 0;
        __syncthreads();
        s[tid] = t + add;
        __syncthreads();
    }
    start[tid] = s[tid] - v;
    if (tid == 255) start[256] = s[255];   // == N_EDGES
}

// ---- per-bucket counting sort + rowptr + dis (one block per bucket) ------
__global__ __launch_bounds__(512) void fine_sort(const int* __restrict__ start,
                                                 const uint2* __restrict__ tmpPad,
                                                 int* __restrict__ rowptr,
                                                 float* __restrict__ dis,
                                                 EdgeRec* __restrict__ ed) {
    __shared__ int   cnt[512];
    __shared__ float wdeg[512];
    __shared__ int   s[512];
    int tid = threadIdx.x;
    int nodeBase = blockIdx.x << 9;
    int bb = start[blockIdx.x];
    int nEdge = start[blockIdx.x + 1] - bb;
    const uint2* tb = tmpPad + (size_t)blockIdx.x * CAP;
    cnt[tid] = 0;
    wdeg[tid] = 0.f;
    __syncthreads();
    for (int e = tid; e < nEdge; e += 512) {
        uint2 r = tb[e];
        int l = (r.y >> 17) & 511;
        atomicAdd(&cnt[l], 1);
        atomicAdd(&wdeg[l], __uint_as_float(r.x));
    }
    __syncthreads();
    int v = cnt[tid];
    s[tid] = v;
    __syncthreads();
    for (int off = 1; off < 512; off <<= 1) {
        int t = s[tid];
        int add = (tid >= off) ? s[tid - off] : 0;
        __syncthreads();
        s[tid] = t + add;
        __syncthreads();
    }
    int excl = s[tid] - v;
    int node = nodeBase + tid;
    if (node < N_NODES) {
        rowptr[node] = bb + excl;
        dis[node] = rsqrtf(wdeg[tid] + 1.0f);   // +1 = self-loop weight
    }
    if (node == N_NODES) rowptr[N_NODES] = N_EDGES;
    cnt[tid] = excl;       // reuse as cursor
    __syncthreads();
    for (int e = tid; e < nEdge; e += 512) {
        uint2 r = tb[e];
        int l = (r.y >> 17) & 511;
        int p = atomicAdd(&cnt[l], 1);
        EdgeRec o;
        o.s = (int)(r.y & 0x1FFFFu);
        o.v = __uint_as_float(r.x);
        ed[bb + p] = o;
    }
}

// ---- h = bf16( dis[row] * (x @ W1) )   [N,128] @ [128,64] ----------------
__global__ __launch_bounds__(256) void mm1_kernel(const float* __restrict__ x,
                                                  const float* __restrict__ W,
                                                  const float* __restrict__ dis,
                                                  unsigned* __restrict__ h) {
    __shared__ __align__(16) float xs[16][IN_C];      // 8 KB
    __shared__ __align__(16) float wsm[IN_C][HID_C];  // 32 KB
    int tid = threadIdx.x;
    {
        float4*       wd = (float4*)&wsm[0][0];
        const float4* wsrc = (const float4*)W;
        for (int i = tid; i < IN_C * HID_C / 4; i += 256) wd[i] = wsrc[i];
        float4*       xd = (float4*)&xs[0][0];
        const float4* xsrc = (const float4*)(x + (size_t)blockIdx.x * 16 * IN_C);
        for (int i = tid; i < 16 * IN_C / 4; i += 256) xd[i] = xsrc[i];
    }
    int rowBase = blockIdx.x * 16;
    __syncthreads();
    int c = tid & 63, rg = tid >> 6;
    const float4* xr0 = (const float4*)&xs[rg * 4 + 0][0];
    const float4* xr1 = (const float4*)&xs[rg * 4 + 1][0];
    const float4* xr2 = (const float4*)&xs[rg * 4 + 2][0];
    const float4* xr3 = (const float4*)&xs[rg * 4 + 3][0];
    float a0 = 0.f, a1 = 0.f, a2 = 0.f, a3 = 0.f;
    #pragma unroll 4
    for (int k4 = 0; k4 < IN_C / 4; ++k4) {
        float4 x0 = xr0[k4], x1 = xr1[k4], x2 = xr2[k4], x3 = xr3[k4];
        float w0 = wsm[4 * k4 + 0][c];
        float w1 = wsm[4 * k4 + 1][c];
        float w2 = wsm[4 * k4 + 2][c];
        float w3 = wsm[4 * k4 + 3][c];
        a0 += x0.x * w0 + x0.y * w1 + x0.z * w2 + x0.w * w3;
        a1 += x1.x * w0 + x1.y * w1 + x1.z * w2 + x1.w * w3;
        a2 += x2.x * w0 + x2.y * w1 + x2.z * w2 + x2.w * w3;
        a3 += x3.x * w0 + x3.y * w1 + x3.z * w2 + x3.w * w3;
    }
    a0 *= dis[rowBase + rg * 4 + 0];
    a1 *= dis[rowBase + rg * 4 + 1];
    a2 *= dis[rowBase + rg * 4 + 2];
    a3 *= dis[rowBase + rg * 4 + 3];
    float o0 = __shfl_xor(a0, 1, 64);
    float o1 = __shfl_xor(a1, 1, 64);
    float o2 = __shfl_xor(a2, 1, 64);
    float o3 = __shfl_xor(a3, 1, 64);
    if ((c & 1) == 0) {
        int ci = c >> 1;
        h[(rowBase + rg * 4 + 0) * 32 + ci] = pack_bf16(a0, o0);
        h[(rowBase + rg * 4 + 1) * 32 + ci] = pack_bf16(a1, o1);
        h[(rowBase + rg * 4 + 2) * 32 + ci] = pack_bf16(a2, o2);
        h[(rowBase + rg * 4 + 3) * 32 + ci] = pack_bf16(a3, o3);
    }
}

// ---- h = bf16( dis[row] * (a @ W2) )   [N,64] @ [64,64] ------------------
__global__ __launch_bounds__(256) void mm2_kernel(const float* __restrict__ a,
                                                  const float* __restrict__ W,
                                                  const float* __restrict__ dis,
                                                  unsigned* __restrict__ h) {
    __shared__ __align__(16) float as[16][HID_C];      // 4 KB
    __shared__ __align__(16) float wsm[HID_C][OUT_C];  // 16 KB
    int tid = threadIdx.x;
    {
        float4*       wd = (float4*)&wsm[0][0];
        const float4* wsrc = (const float4*)W;
        for (int i = tid; i < HID_C * OUT_C / 4; i += 256) wd[i] = wsrc[i];
        float4*       ad = (float4*)&as[0][0];
        const float4* asrc = (const float4*)(a + (size_t)blockIdx.x * 16 * HID_C);
        for (int i = tid; i < 16 * HID_C / 4; i += 256) ad[i] = asrc[i];
    }
    int rowBase = blockIdx.x * 16;
    __syncthreads();
    int c = tid & 63, rg = tid >> 6;
    const float4* xr0 = (const float4*)&as[rg * 4 + 0][0];
    const float4* xr1 = (const float4*)&as[rg * 4 + 1][0];
    const float4* xr2 = (const float4*)&as[rg * 4 + 2][0];
    const float4* xr3 = (const float4*)&as[rg * 4 + 3][0];
    float a0 = 0.f, a1 = 0.f, a2 = 0.f, a3 = 0.f;
    #pragma unroll 4
    for (int k4 = 0; k4 < HID_C / 4; ++k4) {
        float4 x0 = xr0[k4], x1 = xr1[k4], x2 = xr2[k4], x3 = xr3[k4];
        float w0 = wsm[4 * k4 + 0][c];
        float w1 = wsm[4 * k4 + 1][c];
        float w2 = wsm[4 * k4 + 2][c];
        float w3 = wsm[4 * k4 + 3][c];
        a0 += x0.x * w0 + x0.y * w1 + x0.z * w2 + x0.w * w3;
        a1 += x1.x * w0 + x1.y * w1 + x1.z * w2 + x1.w * w3;
        a2 += x2.x * w0 + x2.y * w1 + x2.z * w2 + x2.w * w3;
        a3 += x3.x * w0 + x3.y * w1 + x3.z * w2 + x3.w * w3;
    }
    a0 *= dis[rowBase + rg * 4 + 0];
    a1 *= dis[rowBase + rg * 4 + 1];
    a2 *= dis[rowBase + rg * 4 + 2];
    a3 *= dis[rowBase + rg * 4 + 3];
    float o0 = __shfl_xor(a0, 1, 64);
    float o1 = __shfl_xor(a1, 1, 64);
    float o2 = __shfl_xor(a2, 1, 64);
    float o3 = __shfl_xor(a3, 1, 64);
    if ((c & 1) == 0) {
        int ci = c >> 1;
        h[(rowBase + rg * 4 + 0) * 32 + ci] = pack_bf16(a0, o0);
        h[(rowBase + rg * 4 + 1) * 32 + ci] = pack_bf16(a1, o1);
        h[(rowBase + rg * 4 + 2) * 32 + ci] = pack_bf16(a2, o2);
        h[(rowBase + rg * 4 + 3) * 32 + ci] = pack_bf16(a3, o3);
    }
}

// ---- pipelined batch helpers for agg -------------------------------------
// load 4 EdgeRecs (one per edge-group step) into s/w slots
__device__ __forceinline__ void lde4(const EdgeRec* __restrict__ ed, int e0,
                                     int* s, float* w) {
    #pragma unroll
    for (int j = 0; j < 4; ++j) {
        uint2 q = *(const uint2*)(ed + e0 + j * 8);
        s[j] = (int)q.x;
        w[j] = __uint_as_float(q.y);
    }
}
// issue 4 row gathers (this lane's 16 B slice of each row)
__device__ __forceinline__ void gat4(const char* __restrict__ hb, const int* s,
                                     uint4* u) {
    #pragma unroll
    for (int j = 0; j < 4; ++j)
        u[j] = *(const uint4*)(hb + ((size_t)(unsigned)s[j] << 7));
}
__device__ __forceinline__ void fma4(f32x2* acc2, const uint4* u, const float* w) {
    #pragma unroll
    for (int j = 0; j < 4; ++j) edge_acc(acc2, u[j], w[j]);
}
__device__ __forceinline__ void cpw(float* d, const float* s) {
    #pragma unroll
    for (int j = 0; j < 4; ++j) d[j] = s[j];
}

// ---- CSR aggregate + fused epilogue (bf16 dis-scaled h rows, 128 B) ------
// one wave per node; 8 groups of 8 lanes, one edge per group per step,
// lane reads uint4 = 8 bf16 channels.
// Round-1 change: depth-2 software pipeline over 32-edge batches.
// Steady-state iteration (2 batches): issue gathers for batch i+1 (ed recs
// loaded last iteration), issue ed loads for batch i+2, FMA batch i.
// Breaks the serial ed->gather->fma two-hop latency chain that round-0's
// counters exposed (VALUBusy fell 54->45 with dur unchanged => stall-bound).
// Edge accumulation order is unchanged => bitwise-identical results.
__global__ __launch_bounds__(256) void agg_kernel(const int* __restrict__ rowptr,
                                                  const EdgeRec* __restrict__ ed,
                                                  const unsigned* __restrict__ h,
                                                  const float* __restrict__ dis,
                                                  const float* __restrict__ b,
                                                  float* __restrict__ out,
                                                  int relu) {
    int node = blockIdx.x * 4 + (threadIdx.x >> 6);
    int lane = threadIdx.x & 63;
    int g = lane >> 3;        // edge group 0..7
    int cl = lane & 7;        // channel octet: channels 8*cl .. 8*cl+7
    int beg = rowptr[node];
    int end = rowptr[node + 1];
    const uint4* h16 = (const uint4*)h;             // 8 uint4 per 64-ch row
    const char*  hb  = (const char*)h + (size_t)cl * 16;  // lane's slice base
    // hoisted epilogue operands (broadcast loads, latency hidden by loop)
    float d  = dis[node];
    uint4 us = h16[(size_t)node * 8 + cl];
    f32x2 acc2[4];
    acc2[0] = 0.f; acc2[1] = 0.f; acc2[2] = 0.f; acc2[3] = 0.f;
    int n = end - beg;
    int k = n >> 3;           // 8-edge steps; wave-uniform (one node per wave)
    int nb = k >> 2;          // 32-edge batches
    int e = beg + g;

    int   sP[4];              // newest prefetched ed batch (sources)
    float wP[4];              // its weights
    float wA[4], wB[4];       // weights bound to in-flight gather slots
    uint4 uA[4], uB[4];       // ping-pong gather slots

    if (nb >= 2) {
        lde4(ed, e, sP, wP);            // batch 0 ed
        gat4(hb, sP, uA);               // batch 0 gathers
        cpw(wA, wP);
        lde4(ed, e + 32, sP, wP);       // batch 1 ed
        e += 64;
        int i = nb - 2;                 // batches not yet ed-loaded
        while (i >= 2) {
            gat4(hb, sP, uB);           // batch i+1 gathers
            cpw(wB, wP);
            lde4(ed, e, sP, wP);        // batch i+2 ed
            fma4(acc2, uA, wA);         // consume batch i
            gat4(hb, sP, uA);           // batch i+2 gathers (ed gap covered by fma)
            cpw(wA, wP);
            lde4(ed, e + 32, sP, wP);   // batch i+3 ed
            fma4(acc2, uB, wB);         // consume batch i+1
            e += 64;
            i -= 2;
        }
        if (i == 1) {
            gat4(hb, sP, uB);
            cpw(wB, wP);
            lde4(ed, e, sP, wP);        // last batch ed
            fma4(acc2, uA, wA);
            gat4(hb, sP, uA);
            cpw(wA, wP);
            fma4(acc2, uB, wB);
            fma4(acc2, uA, wA);
            e += 32;
        } else {
            gat4(hb, sP, uB);
            cpw(wB, wP);
            fma4(acc2, uA, wA);
            fma4(acc2, uB, wB);
        }
    } else if (nb == 1) {
        lde4(ed, e, sP, wP);
        gat4(hb, sP, uA);
        fma4(acc2, uA, wP);
        e += 32;
    }
    // leftover full steps (k & 3, wave-uniform, 0..3 of them)
    int ks = k & 3;
    for (int j = 0; j < ks; ++j, e += 8) {
        uint2 q = *(const uint2*)(ed + e);
        uint4 u = *(const uint4*)(hb + ((size_t)q.x << 7));
        edge_acc(acc2, u, __uint_as_float(q.y));
    }
    // masked tail (deg & 7 edges)
    if (g < (n & 7)) {
        uint2 q = *(const uint2*)(ed + e);
        uint4 u = *(const uint4*)(hb + ((size_t)q.x << 7));
        edge_acc(acc2, u, __uint_as_float(q.y));
    }
    float acc[8] = { acc2[0].x, acc2[0].y, acc2[1].x, acc2[1].y,
                     acc2[2].x, acc2[2].y, acc2[3].x, acc2[3].y };
    #pragma unroll
    for (int kk = 0; kk < 8; ++kk) {
        acc[kk] += __shfl_xor(acc[kk], 8, 64);
        acc[kk] += __shfl_xor(acc[kk], 16, 64);
        acc[kk] += __shfl_xor(acc[kk], 32, 64);
    }
    if (g == 0) {
        float hs[8] = { bf_lo(us.x), bf_hi(us.x), bf_lo(us.y), bf_hi(us.y),
                        bf_lo(us.z), bf_hi(us.z), bf_lo(us.w), bf_hi(us.w) };
        const float4* b4 = (const float4*)b;
        float4 bv0 = b4[cl * 2], bv1 = b4[cl * 2 + 1];
        float4 v0, v1;
        v0.x = d * (acc[0] + hs[0]) + bv0.x;
        v0.y = d * (acc[1] + hs[1]) + bv0.y;
        v0.z = d * (acc[2] + hs[2]) + bv0.z;
        v0.w = d * (acc[3] + hs[3]) + bv0.w;
        v1.x = d * (acc[4] + hs[4]) + bv1.x;
        v1.y = d * (acc[5] + hs[5]) + bv1.y;
        v1.z = d * (acc[6] + hs[6]) + bv1.z;
        v1.w = d * (acc[7] + hs[7]) + bv1.w;
        if (relu) {
            v0.x = fmaxf(v0.x, 0.f); v0.y = fmaxf(v0.y, 0.f);
            v0.z = fmaxf(v0.z, 0.f); v0.w = fmaxf(v0.w, 0.f);
            v1.x = fmaxf(v1.x, 0.f); v1.y = fmaxf(v1.y, 0.f);
            v1.z = fmaxf(v1.z, 0.f); v1.w = fmaxf(v1.w, 0.f);
        }
        float4* o4 = (float4*)out;
        o4[node * 16 + cl * 2]     = v0;
        o4[node * 16 + cl * 2 + 1] = v1;
    }
}

extern "C" void kernel_launch(void* const* d_in, const int* in_sizes, int n_in,
                              void* d_out, int out_size, void* d_ws, size_t ws_size,
                              hipStream_t stream) {
    const float* x  = (const float*)d_in[0];
    const int*   ei = (const int*)d_in[1];   // [2, E]: sources then targets
    const float* ew = (const float*)d_in[2];
    const float* W1 = (const float*)d_in[3];
    const float* b1 = (const float*)d_in[4];
    const float* W2 = (const float*)d_in[5];
    const float* b2 = (const float*)d_in[6];
    float* out = (float*)d_out;

    // workspace carve-up (256 B aligned). tmpPad (28.9 MB, padded buckets)
    // is dead after fine_sort; bf16 h (12.8 MB) + f32 a (25.6 MB) overlay it.
    char* p = (char*)d_ws;
    auto carve = [&](size_t bytes) { char* r = p; p += (bytes + 255) & ~(size_t)255; return r; };
    float*    dis     = (float*)carve(N_NODES * 4);
    int*      rowptr  = (int*)carve((N_NODES + 1) * 4);
    int*      start   = (int*)carve(257 * 4);
    int*      gcursor = (int*)carve(256 * 4);
    EdgeRec*  ed      = (EdgeRec*)carve((size_t)N_EDGES * 8);
    size_t    r2sz    = (size_t)NBUCKET * CAP * 8;                 // 28.9 MB
    size_t    hasz    = (size_t)N_NODES * 64 * 6;                  // 38.4 MB
    char*     r2      = carve(r2sz > hasz ? r2sz : hasz);
    uint2*    tmpPad  = (uint2*)r2;
    unsigned* h       = (unsigned*)r2;                             // 12.8 MB
    float*    a       = (float*)(r2 + (size_t)N_NODES * 64 * 2);   // 25.6 MB

    // --- CSR build: direct padded reservation, no pre-histogram ---
    hipMemsetAsync(gcursor, 0, 256 * sizeof(int), stream);
    scatter_coarse<<<SC_GRID, 256, 0, stream>>>(ei, ew, gcursor, tmpPad);
    bucket_scan<<<1, 256, 0, stream>>>(gcursor, start);
    fine_sort<<<NBUCKET, 512, 0, stream>>>(start, tmpPad, rowptr, dis, ed);

    // --- layer 1: h = bf16(dis.(x@W1)) ; a = relu(agg(h) + b1) ---
    mm1_kernel<<<N_NODES / 16, 256, 0, stream>>>(x, W1, dis, h);
    agg_kernel<<<N_NODES / 4, 256, 0, stream>>>(rowptr, ed, h, dis, b1, a, 1);

    // --- layer 2: h = bf16(dis.(a@W2)) ; out = agg(h) + b2 ---
    mm2_kernel<<<N_NODES / 16, 256, 0, stream>>>(a, W2, dis, h);
    agg_kernel<<<N_NODES / 4, 256, 0, stream>>>(rowptr, ed, h, dis, b2, out, 0);
}

// Round 3
// 376.950 us; speedup vs baseline: 1.3639x; 1.3639x over previous
//
#include <hip/hip_runtime.h>
#include <hip/hip_bf16.h>

#define N_NODES 100000
#define N_EDGES 3200000
#define IN_C 128
#define HID_C 64
#define OUT_C 64

#define NBUCKET 196          // ceil(N_NODES / 512); bucket = target >> 9
#define SC_EDGES 4096        // edges per scatter block
#define SC_GRID 782          // ceil(E / SC_EDGES)
#define CAP 18432            // padded bucket capacity (mean 16384 + 16 sigma)

struct EdgeRec { int s; float v; };   // source node, raw edge weight w

typedef float f32x2 __attribute__((ext_vector_type(2)));

// staged record: 8 B. x = f32 bits of w; y = s (17 bits) | t_local<<17 (9 bits)
__device__ __forceinline__ unsigned pack_bf16(float lo, float hi) {
    unsigned short l = __hip_bfloat16_raw(__float2bfloat16(lo)).x;
    unsigned short h = __hip_bfloat16_raw(__float2bfloat16(hi)).x;
    return ((unsigned)h << 16) | l;
}
__device__ __forceinline__ float bf_lo(unsigned u) {
    union { unsigned u; float f; } c; c.u = u << 16; return c.f;
}
__device__ __forceinline__ float bf_hi(unsigned u) {
    union { unsigned u; float f; } c; c.u = u & 0xffff0000u; return c.f;
}
// unpack a bf16 pair into an f32x2 register pair (lshl + and, exact)
__device__ __forceinline__ f32x2 bfp(unsigned u) {
    union { unsigned u; float f; } lo, hi;
    lo.u = u << 16; hi.u = u & 0xffff0000u;
    f32x2 r; r.x = lo.f; r.y = hi.f; return r;
}
// packed f32 FMA: acc = a*w + acc  (v_pk_fma_f32, full-rate on gfx950)
__device__ __forceinline__ void pk_fma(f32x2& acc, f32x2 a, f32x2 w) {
    asm("v_pk_fma_f32 %0, %1, %2, %0" : "+v"(acc) : "v"(a), "v"(w));
}
// accumulate one edge's 8 channels (one uint4) with weight w
__device__ __forceinline__ void edge_acc(f32x2* acc2, uint4 u, float w) {
    f32x2 wv; wv.x = w; wv.y = w;
    pk_fma(acc2[0], bfp(u.x), wv);
    pk_fma(acc2[1], bfp(u.y), wv);
    pk_fma(acc2[2], bfp(u.z), wv);
    pk_fma(acc2[3], bfp(u.w), wv);
}

// ---- coarse scatter: edges -> padded bucket-major staging ----------------
__global__ __launch_bounds__(256) void scatter_coarse(const int* __restrict__ ei,
                                                      const float* __restrict__ ew,
                                                      int* __restrict__ gcursor,
                                                      uint2* __restrict__ tmp) {
    __shared__ int hist[256];
    __shared__ int scan[256];
    __shared__ int lcur[256];
    __shared__ int adj[256];
    __shared__ uint2 rec[SC_EDGES];           // 32 KB
    __shared__ unsigned char bk[SC_EDGES];    // 4 KB
    int tid = threadIdx.x;
    hist[tid] = 0;
    __syncthreads();
    int base = blockIdx.x * SC_EDGES;
    unsigned ys[16];
    float    ws[16];
    int      bs[16];
    for (int i = 0; i < 16; ++i) {
        int e = base + i * 256 + tid;
        if (e < N_EDGES) {
            int t = ei[N_EDGES + e];
            bs[i] = t >> 9;
            ys[i] = (unsigned)ei[e] | ((unsigned)(t & 511) << 17);
            ws[i] = ew[e];
            atomicAdd(&hist[bs[i]], 1);
        } else bs[i] = -1;
    }
    __syncthreads();
    // exclusive scan of hist
    int v = hist[tid];
    scan[tid] = v;
    __syncthreads();
    for (int off = 1; off < 256; off <<= 1) {
        int t = scan[tid];
        int add = (tid >= off) ? scan[tid - off] : 0;
        __syncthreads();
        scan[tid] = t + add;
        __syncthreads();
    }
    int excl = scan[tid] - v;
    int gb = (v > 0) ? atomicAdd(&gcursor[tid], v) : 0;
    lcur[tid] = excl;
    adj[tid] = tid * CAP + gb - excl;  // global slot for LDS slot j: adj[b]+j
    __syncthreads();
    // place edges into LDS bucket-major
    for (int i = 0; i < 16; ++i) {
        if (bs[i] >= 0) {
            int j = atomicAdd(&lcur[bs[i]], 1);
            rec[j] = make_uint2(__float_as_uint(ws[i]), ys[i]);
            bk[j] = (unsigned char)bs[i];
        }
    }
    __syncthreads();
    // run-coalesced write-out
    int count = N_EDGES - base;
    if (count > SC_EDGES) count = SC_EDGES;
    for (int j = tid; j < count; j += 256) {
        int b = bk[j];
        tmp[adj[b] + j] = rec[j];
    }
}

// ---- exclusive scan of bucket counts -> dense ed bases -------------------
__global__ __launch_bounds__(256) void bucket_scan(const int* __restrict__ gcnt,
                                                   int* __restrict__ start) {
    __shared__ int s[256];
    int tid = threadIdx.x;
    int v = gcnt[tid];
    s[tid] = v;
    __syncthreads();
    for (int off = 1; off < 256; off <<= 1) {
        int t = s[tid];
        int add = (tid >= off) ? s[tid - off] : 0;
        __syncthreads();
        s[tid] = t + add;
        __syncthreads();
    }
    start[tid] = s[tid] - v;
    if (tid == 255) start[256] = s[255];   // == N_EDGES
}

// ---- per-bucket counting sort + rowptr + dis (one block per bucket) ------
__global__ __launch_bounds__(512) void fine_sort(const int* __restrict__ start,
                                                 const uint2* __restrict__ tmpPad,
                                                 int* __restrict__ rowptr,
                                                 float* __restrict__ dis,
                                                 EdgeRec* __restrict__ ed) {
    __shared__ int   cnt[512];
    __shared__ float wdeg[512];
    __shared__ int   s[512];
    int tid = threadIdx.x;
    int nodeBase = blockIdx.x << 9;
    int bb = start[blockIdx.x];
    int nEdge = start[blockIdx.x + 1] - bb;
    const uint2* tb = tmpPad + (size_t)blockIdx.x * CAP;
    cnt[tid] = 0;
    wdeg[tid] = 0.f;
    __syncthreads();
    for (int e = tid; e < nEdge; e += 512) {
        uint2 r = tb[e];
        int l = (r.y >> 17) & 511;
        atomicAdd(&cnt[l], 1);
        atomicAdd(&wdeg[l], __uint_as_float(r.x));
    }
    __syncthreads();
    int v = cnt[tid];
    s[tid] = v;
    __syncthreads();
    for (int off = 1; off < 512; off <<= 1) {
        int t = s[tid];
        int add = (tid >= off) ? s[tid - off] : 0;
        __syncthreads();
        s[tid] = t + add;
        __syncthreads();
    }
    int excl = s[tid] - v;
    int node = nodeBase + tid;
    if (node < N_NODES) {
        rowptr[node] = bb + excl;
        dis[node] = rsqrtf(wdeg[tid] + 1.0f);   // +1 = self-loop weight
    }
    if (node == N_NODES) rowptr[N_NODES] = N_EDGES;
    cnt[tid] = excl;       // reuse as cursor
    __syncthreads();
    for (int e = tid; e < nEdge; e += 512) {
        uint2 r = tb[e];
        int l = (r.y >> 17) & 511;
        int p = atomicAdd(&cnt[l], 1);
        EdgeRec o;
        o.s = (int)(r.y & 0x1FFFFu);
        o.v = __uint_as_float(r.x);
        ed[bb + p] = o;
    }
}

// ---- h = bf16( dis[row] * (x @ W1) )   [N,128] @ [128,64] ----------------
__global__ __launch_bounds__(256) void mm1_kernel(const float* __restrict__ x,
                                                  const float* __restrict__ W,
                                                  const float* __restrict__ dis,
                                                  unsigned* __restrict__ h) {
    __shared__ __align__(16) float xs[16][IN_C];      // 8 KB
    __shared__ __align__(16) float wsm[IN_C][HID_C];  // 32 KB
    int tid = threadIdx.x;
    {
        float4*       wd = (float4*)&wsm[0][0];
        const float4* wsrc = (const float4*)W;
        for (int i = tid; i < IN_C * HID_C / 4; i += 256) wd[i] = wsrc[i];
        float4*       xd = (float4*)&xs[0][0];
        const float4* xsrc = (const float4*)(x + (size_t)blockIdx.x * 16 * IN_C);
        for (int i = tid; i < 16 * IN_C / 4; i += 256) xd[i] = xsrc[i];
    }
    int rowBase = blockIdx.x * 16;
    __syncthreads();
    int c = tid & 63, rg = tid >> 6;
    const float4* xr0 = (const float4*)&xs[rg * 4 + 0][0];
    const float4* xr1 = (const float4*)&xs[rg * 4 + 1][0];
    const float4* xr2 = (const float4*)&xs[rg * 4 + 2][0];
    const float4* xr3 = (const float4*)&xs[rg * 4 + 3][0];
    float a0 = 0.f, a1 = 0.f, a2 = 0.f, a3 = 0.f;
    #pragma unroll 4
    for (int k4 = 0; k4 < IN_C / 4; ++k4) {
        float4 x0 = xr0[k4], x1 = xr1[k4], x2 = xr2[k4], x3 = xr3[k4];
        float w0 = wsm[4 * k4 + 0][c];
        float w1 = wsm[4 * k4 + 1][c];
        float w2 = wsm[4 * k4 + 2][c];
        float w3 = wsm[4 * k4 + 3][c];
        a0 += x0.x * w0 + x0.y * w1 + x0.z * w2 + x0.w * w3;
        a1 += x1.x * w0 + x1.y * w1 + x1.z * w2 + x1.w * w3;
        a2 += x2.x * w0 + x2.y * w1 + x2.z * w2 + x2.w * w3;
        a3 += x3.x * w0 + x3.y * w1 + x3.z * w2 + x3.w * w3;
    }
    a0 *= dis[rowBase + rg * 4 + 0];
    a1 *= dis[rowBase + rg * 4 + 1];
    a2 *= dis[rowBase + rg * 4 + 2];
    a3 *= dis[rowBase + rg * 4 + 3];
    float o0 = __shfl_xor(a0, 1, 64);
    float o1 = __shfl_xor(a1, 1, 64);
    float o2 = __shfl_xor(a2, 1, 64);
    float o3 = __shfl_xor(a3, 1, 64);
    if ((c & 1) == 0) {
        int ci = c >> 1;
        h[(rowBase + rg * 4 + 0) * 32 + ci] = pack_bf16(a0, o0);
        h[(rowBase + rg * 4 + 1) * 32 + ci] = pack_bf16(a1, o1);
        h[(rowBase + rg * 4 + 2) * 32 + ci] = pack_bf16(a2, o2);
        h[(rowBase + rg * 4 + 3) * 32 + ci] = pack_bf16(a3, o3);
    }
}

// ---- h = bf16( dis[row] * (a @ W2) )   [N,64] @ [64,64] ------------------
__global__ __launch_bounds__(256) void mm2_kernel(const float* __restrict__ a,
                                                  const float* __restrict__ W,
                                                  const float* __restrict__ dis,
                                                  unsigned* __restrict__ h) {
    __shared__ __align__(16) float as[16][HID_C];      // 4 KB
    __shared__ __align__(16) float wsm[HID_C][OUT_C];  // 16 KB
    int tid = threadIdx.x;
    {
        float4*       wd = (float4*)&wsm[0][0];
        const float4* wsrc = (const float4*)W;
        for (int i = tid; i < HID_C * OUT_C / 4; i += 256) wd[i] = wsrc[i];
        float4*       ad = (float4*)&as[0][0];
        const float4* asrc = (const float4*)(a + (size_t)blockIdx.x * 16 * HID_C);
        for (int i = tid; i < 16 * HID_C / 4; i += 256) ad[i] = asrc[i];
    }
    int rowBase = blockIdx.x * 16;
    __syncthreads();
    int c = tid & 63, rg = tid >> 6;
    const float4* xr0 = (const float4*)&as[rg * 4 + 0][0];
    const float4* xr1 = (const float4*)&as[rg * 4 + 1][0];
    const float4* xr2 = (const float4*)&as[rg * 4 + 2][0];
    const float4* xr3 = (const float4*)&as[rg * 4 + 3][0];
    float a0 = 0.f, a1 = 0.f, a2 = 0.f, a3 = 0.f;
    #pragma unroll 4
    for (int k4 = 0; k4 < HID_C / 4; ++k4) {
        float4 x0 = xr0[k4], x1 = xr1[k4], x2 = xr2[k4], x3 = xr3[k4];
        float w0 = wsm[4 * k4 + 0][c];
        float w1 = wsm[4 * k4 + 1][c];
        float w2 = wsm[4 * k4 + 2][c];
        float w3 = wsm[4 * k4 + 3][c];
        a0 += x0.x * w0 + x0.y * w1 + x0.z * w2 + x0.w * w3;
        a1 += x1.x * w0 + x1.y * w1 + x1.z * w2 + x1.w * w3;
        a2 += x2.x * w0 + x2.y * w1 + x2.z * w2 + x2.w * w3;
        a3 += x3.x * w0 + x3.y * w1 + x3.z * w2 + x3.w * w3;
    }
    a0 *= dis[rowBase + rg * 4 + 0];
    a1 *= dis[rowBase + rg * 4 + 1];
    a2 *= dis[rowBase + rg * 4 + 2];
    a3 *= dis[rowBase + rg * 4 + 3];
    float o0 = __shfl_xor(a0, 1, 64);
    float o1 = __shfl_xor(a1, 1, 64);
    float o2 = __shfl_xor(a2, 1, 64);
    float o3 = __shfl_xor(a3, 1, 64);
    if ((c & 1) == 0) {
        int ci = c >> 1;
        h[(rowBase + rg * 4 + 0) * 32 + ci] = pack_bf16(a0, o0);
        h[(rowBase + rg * 4 + 1) * 32 + ci] = pack_bf16(a1, o1);
        h[(rowBase + rg * 4 + 2) * 32 + ci] = pack_bf16(a2, o2);
        h[(rowBase + rg * 4 + 3) * 32 + ci] = pack_bf16(a3, o3);
    }
}

// ---- CSR aggregate + fused epilogue (bf16 dis-scaled h rows, 128 B) ------
// one wave per node; 8 groups of 8 lanes, one edge per group per step,
// lane reads uint4 = 8 bf16 channels.
// Round-2 structure (post-mortems of R0/R1):
//  * R1 showed the kernel is memory-LATENCY bound and lives on occupancy:
//    VGPR 72 halved waves/SIMD (64-VGPR cliff) and doubled duration.
//    => hard rule: <=64 VGPR, pinned via __launch_bounds__(256, 8).
//  * All rows are mask-padded to whole 32-edge batches: out-of-range
//    steps/lanes clamp the ed index to n-1 and use weight 0 (0 x finite
//    = 0; clamped reads stay inside ed[] and L1-hit). This removes the
//    serial leftover-step loop and divergent tail (~2 extra full-latency
//    round-trips per wave) that dominated the R0 structure.
//  * ed recs for batch i+1 prefetch into the same q regs during batch i's
//    gather wait (8 VGPRs, no ping-pong gather buffers).
// Accumulation order of active edges is unchanged => identical numerics.
__global__ __launch_bounds__(256, 8) void agg_kernel(const int* __restrict__ rowptr,
                                                     const EdgeRec* __restrict__ ed,
                                                     const unsigned* __restrict__ h,
                                                     const float* __restrict__ dis,
                                                     const float* __restrict__ b,
                                                     float* __restrict__ out,
                                                     int relu) {
    int node = blockIdx.x * 4 + (threadIdx.x >> 6);
    int lane = threadIdx.x & 63;
    int g = lane >> 3;        // edge group 0..7
    int cl = lane & 7;        // channel octet: channels 8*cl .. 8*cl+7
    int beg = rowptr[node];
    int end = rowptr[node + 1];
    const uint4* h16 = (const uint4*)h;                   // 8 uint4 per row
    const char*  hb  = (const char*)h + (size_t)cl * 16;  // lane's slice base
    // hoisted epilogue operands (broadcast loads, latency hidden by loop)
    float d  = dis[node];
    uint4 us = h16[(size_t)node * 8 + cl];
    f32x2 acc2[4];
    acc2[0] = 0.f; acc2[1] = 0.f; acc2[2] = 0.f; acc2[3] = 0.f;
    int n = end - beg;            // in-degree (excl self)
    int nb = (n + 31) >> 5;       // 32-edge batches, wave-uniform
    int nm1 = n - 1;
    uint2 q0, q1, q2, q3;
    if (nb > 0) {
        q0 = *(const uint2*)(ed + beg + min(g,      nm1));
        q1 = *(const uint2*)(ed + beg + min(g + 8,  nm1));
        q2 = *(const uint2*)(ed + beg + min(g + 16, nm1));
        q3 = *(const uint2*)(ed + beg + min(g + 24, nm1));
        for (int bt = 0; bt < nb; ++bt) {
            int ob = (bt << 5) + g;
            // weights masked before q is overwritten by the prefetch
            float w0 = (ob      < n) ? __uint_as_float(q0.y) : 0.f;
            float w1 = (ob + 8  < n) ? __uint_as_float(q1.y) : 0.f;
            float w2 = (ob + 16 < n) ? __uint_as_float(q2.y) : 0.f;
            float w3 = (ob + 24 < n) ? __uint_as_float(q3.y) : 0.f;
            // 4 gathers in flight (addresses read q.x at issue)
            uint4 u0 = *(const uint4*)(hb + ((size_t)(unsigned)q0.x << 7));
            uint4 u1 = *(const uint4*)(hb + ((size_t)(unsigned)q1.x << 7));
            uint4 u2 = *(const uint4*)(hb + ((size_t)(unsigned)q2.x << 7));
            uint4 u3 = *(const uint4*)(hb + ((size_t)(unsigned)q3.x << 7));
            // prefetch next batch's ed recs under the gather latency
            if (bt + 1 < nb) {
                int on = ob + 32;
                q0 = *(const uint2*)(ed + beg + min(on,      nm1));
                q1 = *(const uint2*)(ed + beg + min(on + 8,  nm1));
                q2 = *(const uint2*)(ed + beg + min(on + 16, nm1));
                q3 = *(const uint2*)(ed + beg + min(on + 24, nm1));
            }
            edge_acc(acc2, u0, w0);
            edge_acc(acc2, u1, w1);
            edge_acc(acc2, u2, w2);
            edge_acc(acc2, u3, w3);
        }
    }
    float acc[8] = { acc2[0].x, acc2[0].y, acc2[1].x, acc2[1].y,
                     acc2[2].x, acc2[2].y, acc2[3].x, acc2[3].y };
    #pragma unroll
    for (int kk = 0; kk < 8; ++kk) {
        acc[kk] += __shfl_xor(acc[kk], 8, 64);
        acc[kk] += __shfl_xor(acc[kk], 16, 64);
        acc[kk] += __shfl_xor(acc[kk], 32, 64);
    }
    if (g == 0) {
        float hs[8] = { bf_lo(us.x), bf_hi(us.x), bf_lo(us.y), bf_hi(us.y),
                        bf_lo(us.z), bf_hi(us.z), bf_lo(us.w), bf_hi(us.w) };
        const float4* b4 = (const float4*)b;
        float4 bv0 = b4[cl * 2], bv1 = b4[cl * 2 + 1];
        float4 v0, v1;
        v0.x = d * (acc[0] + hs[0]) + bv0.x;
        v0.y = d * (acc[1] + hs[1]) + bv0.y;
        v0.z = d * (acc[2] + hs[2]) + bv0.z;
        v0.w = d * (acc[3] + hs[3]) + bv0.w;
        v1.x = d * (acc[4] + hs[4]) + bv1.x;
        v1.y = d * (acc[5] + hs[5]) + bv1.y;
        v1.z = d * (acc[6] + hs[6]) + bv1.z;
        v1.w = d * (acc[7] + hs[7]) + bv1.w;
        if (relu) {
            v0.x = fmaxf(v0.x, 0.f); v0.y = fmaxf(v0.y, 0.f);
            v0.z = fmaxf(v0.z, 0.f); v0.w = fmaxf(v0.w, 0.f);
            v1.x = fmaxf(v1.x, 0.f); v1.y = fmaxf(v1.y, 0.f);
            v1.z = fmaxf(v1.z, 0.f); v1.w = fmaxf(v1.w, 0.f);
        }
        float4* o4 = (float4*)out;
        o4[node * 16 + cl * 2]     = v0;
        o4[node * 16 + cl * 2 + 1] = v1;
    }
}

extern "C" void kernel_launch(void* const* d_in, const int* in_sizes, int n_in,
                              void* d_out, int out_size, void* d_ws, size_t ws_size,
                              hipStream_t stream) {
    const float* x  = (const float*)d_in[0];
    const int*   ei = (const int*)d_in[1];   // [2, E]: sources then targets
    const float* ew = (const float*)d_in[2];
    const float* W1 = (const float*)d_in[3];
    const float* b1 = (const float*)d_in[4];
    const float* W2 = (const float*)d_in[5];
    const float* b2 = (const float*)d_in[6];
    float* out = (float*)d_out;

    // workspace carve-up (256 B aligned). tmpPad (28.9 MB, padded buckets)
    // is dead after fine_sort; bf16 h (12.8 MB) + f32 a (25.6 MB) overlay it.
    char* p = (char*)d_ws;
    auto carve = [&](size_t bytes) { char* r = p; p += (bytes + 255) & ~(size_t)255; return r; };
    float*    dis     = (float*)carve(N_NODES * 4);
    int*      rowptr  = (int*)carve((N_NODES + 1) * 4);
    int*      start   = (int*)carve(257 * 4);
    int*      gcursor = (int*)carve(256 * 4);
    EdgeRec*  ed      = (EdgeRec*)carve((size_t)N_EDGES * 8);
    size_t    r2sz    = (size_t)NBUCKET * CAP * 8;                 // 28.9 MB
    size_t    hasz    = (size_t)N_NODES * 64 * 6;                  // 38.4 MB
    char*     r2      = carve(r2sz > hasz ? r2sz : hasz);
    uint2*    tmpPad  = (uint2*)r2;
    unsigned* h       = (unsigned*)r2;                             // 12.8 MB
    float*    a       = (float*)(r2 + (size_t)N_NODES * 64 * 2);   // 25.6 MB

    // --- CSR build: direct padded reservation, no pre-histogram ---
    hipMemsetAsync(gcursor, 0, 256 * sizeof(int), stream);
    scatter_coarse<<<SC_GRID, 256, 0, stream>>>(ei, ew, gcursor, tmpPad);
    bucket_scan<<<1, 256, 0, stream>>>(gcursor, start);
    fine_sort<<<NBUCKET, 512, 0, stream>>>(start, tmpPad, rowptr, dis, ed);

    // --- layer 1: h = bf16(dis.(x@W1)) ; a = relu(agg(h) + b1) ---
    mm1_kernel<<<N_NODES / 16, 256, 0, stream>>>(x, W1, dis, h);
    agg_kernel<<<N_NODES / 4, 256, 0, stream>>>(rowptr, ed, h, dis, b1, a, 1);

    // --- layer 2: h = bf16(dis.(a@W2)) ; out = agg(h) + b2 ---
    mm2_kernel<<<N_NODES / 16, 256, 0, stream>>>(a, W2, dis, h);
    agg_kernel<<<N_NODES / 4, 256, 0, stream>>>(rowptr, ed, h, dis, b2, out, 0);
}

// Round 4
// 352.633 us; speedup vs baseline: 1.4579x; 1.0690x over previous
//
#include <hip/hip_runtime.h>
#include <hip/hip_bf16.h>

#define N_NODES 100000
#define N_EDGES 3200000
#define IN_C 128
#define HID_C 64
#define OUT_C 64

#define NBUCKET 196          // ceil(N_NODES / 512); bucket = target >> 9
#define SC_EDGES 4096        // edges per scatter block
#define SC_GRID 782          // ceil(E / SC_EDGES)
#define CAP 18432            // padded bucket capacity (mean 16384 + 16 sigma)

struct EdgeRec { int s; float v; };   // source node, raw edge weight w

typedef float f32x2 __attribute__((ext_vector_type(2)));
typedef float f32x4 __attribute__((ext_vector_type(4)));
typedef short bf16x8 __attribute__((ext_vector_type(8)));
union F8 { uint4 u; bf16x8 f; };

// staged record: 8 B. x = f32 bits of w; y = s (17 bits) | t_local<<17 (9 bits)
__device__ __forceinline__ unsigned pack_bf16(float lo, float hi) {
    unsigned short l = __hip_bfloat16_raw(__float2bfloat16(lo)).x;
    unsigned short h = __hip_bfloat16_raw(__float2bfloat16(hi)).x;
    return ((unsigned)h << 16) | l;
}
__device__ __forceinline__ float bf_lo(unsigned u) {
    union { unsigned u; float f; } c; c.u = u << 16; return c.f;
}
__device__ __forceinline__ float bf_hi(unsigned u) {
    union { unsigned u; float f; } c; c.u = u & 0xffff0000u; return c.f;
}
// unpack a bf16 pair into an f32x2 register pair (lshl + and, exact)
__device__ __forceinline__ f32x2 bfp(unsigned u) {
    union { unsigned u; float f; } lo, hi;
    lo.u = u << 16; hi.u = u & 0xffff0000u;
    f32x2 r; r.x = lo.f; r.y = hi.f; return r;
}
// packed f32 FMA: acc = a*w + acc  (v_pk_fma_f32, full-rate on gfx950)
__device__ __forceinline__ void pk_fma(f32x2& acc, f32x2 a, f32x2 w) {
    asm("v_pk_fma_f32 %0, %1, %2, %0" : "+v"(acc) : "v"(a), "v"(w));
}
// accumulate one edge's 8 channels (one uint4) with weight w
__device__ __forceinline__ void edge_acc(f32x2* acc2, uint4 u, float w) {
    f32x2 wv; wv.x = w; wv.y = w;
    pk_fma(acc2[0], bfp(u.x), wv);
    pk_fma(acc2[1], bfp(u.y), wv);
    pk_fma(acc2[2], bfp(u.z), wv);
    pk_fma(acc2[3], bfp(u.w), wv);
}
// v_cvt_pk_bf16_f32: two f32 -> packed bf16 pair (lo in low half), RNE
__device__ __forceinline__ unsigned cvt_pk_bf16(float lo, float hi) {
    unsigned r;
    asm("v_cvt_pk_bf16_f32 %0, %1, %2" : "=v"(r) : "v"(lo), "v"(hi));
    return r;
}
// split 8 f32 into bf16 hi-frag + bf16 lo-frag (residual), packed as uint4
__device__ __forceinline__ void split_frag(const float* f, uint4& hi4, uint4& lo4) {
    unsigned hi[4], lo[4];
    #pragma unroll
    for (int p = 0; p < 4; ++p) {
        hi[p] = cvt_pk_bf16(f[2 * p], f[2 * p + 1]);
        float r0 = f[2 * p]     - bf_lo(hi[p]);
        float r1 = f[2 * p + 1] - bf_hi(hi[p]);
        lo[p] = cvt_pk_bf16(r0, r1);
    }
    hi4 = make_uint4(hi[0], hi[1], hi[2], hi[3]);
    lo4 = make_uint4(lo[0], lo[1], lo[2], lo[3]);
}

// ---- coarse scatter: edges -> padded bucket-major staging ----------------
__global__ __launch_bounds__(256) void scatter_coarse(const int* __restrict__ ei,
                                                      const float* __restrict__ ew,
                                                      int* __restrict__ gcursor,
                                                      uint2* __restrict__ tmp) {
    __shared__ int hist[256];
    __shared__ int scan[256];
    __shared__ int lcur[256];
    __shared__ int adj[256];
    __shared__ uint2 rec[SC_EDGES];           // 32 KB
    __shared__ unsigned char bk[SC_EDGES];    // 4 KB
    int tid = threadIdx.x;
    hist[tid] = 0;
    __syncthreads();
    int base = blockIdx.x * SC_EDGES;
    unsigned ys[16];
    float    ws[16];
    int      bs[16];
    for (int i = 0; i < 16; ++i) {
        int e = base + i * 256 + tid;
        if (e < N_EDGES) {
            int t = ei[N_EDGES + e];
            bs[i] = t >> 9;
            ys[i] = (unsigned)ei[e] | ((unsigned)(t & 511) << 17);
            ws[i] = ew[e];
            atomicAdd(&hist[bs[i]], 1);
        } else bs[i] = -1;
    }
    __syncthreads();
    // exclusive scan of hist
    int v = hist[tid];
    scan[tid] = v;
    __syncthreads();
    for (int off = 1; off < 256; off <<= 1) {
        int t = scan[tid];
        int add = (tid >= off) ? scan[tid - off] : 0;
        __syncthreads();
        scan[tid] = t + add;
        __syncthreads();
    }
    int excl = scan[tid] - v;
    int gb = (v > 0) ? atomicAdd(&gcursor[tid], v) : 0;
    lcur[tid] = excl;
    adj[tid] = tid * CAP + gb - excl;  // global slot for LDS slot j: adj[b]+j
    __syncthreads();
    // place edges into LDS bucket-major
    for (int i = 0; i < 16; ++i) {
        if (bs[i] >= 0) {
            int j = atomicAdd(&lcur[bs[i]], 1);
            rec[j] = make_uint2(__float_as_uint(ws[i]), ys[i]);
            bk[j] = (unsigned char)bs[i];
        }
    }
    __syncthreads();
    // run-coalesced write-out
    int count = N_EDGES - base;
    if (count > SC_EDGES) count = SC_EDGES;
    for (int j = tid; j < count; j += 256) {
        int b = bk[j];
        tmp[adj[b] + j] = rec[j];
    }
}

// ---- exclusive scan of bucket counts -> dense ed bases -------------------
__global__ __launch_bounds__(256) void bucket_scan(const int* __restrict__ gcnt,
                                                   int* __restrict__ start) {
    __shared__ int s[256];
    int tid = threadIdx.x;
    int v = gcnt[tid];
    s[tid] = v;
    __syncthreads();
    for (int off = 1; off < 256; off <<= 1) {
        int t = s[tid];
        int add = (tid >= off) ? s[tid - off] : 0;
        __syncthreads();
        s[tid] = t + add;
        __syncthreads();
    }
    start[tid] = s[tid] - v;
    if (tid == 255) start[256] = s[255];   // == N_EDGES
}

// ---- per-bucket counting sort + rowptr + dis (one block per bucket) ------
__global__ __launch_bounds__(512) void fine_sort(const int* __restrict__ start,
                                                 const uint2* __restrict__ tmpPad,
                                                 int* __restrict__ rowptr,
                                                 float* __restrict__ dis,
                                                 EdgeRec* __restrict__ ed) {
    __shared__ int   cnt[512];
    __shared__ float wdeg[512];
    __shared__ int   s[512];
    int tid = threadIdx.x;
    int nodeBase = blockIdx.x << 9;
    int bb = start[blockIdx.x];
    int nEdge = start[blockIdx.x + 1] - bb;
    const uint2* tb = tmpPad + (size_t)blockIdx.x * CAP;
    cnt[tid] = 0;
    wdeg[tid] = 0.f;
    __syncthreads();
    for (int e = tid; e < nEdge; e += 512) {
        uint2 r = tb[e];
        int l = (r.y >> 17) & 511;
        atomicAdd(&cnt[l], 1);
        atomicAdd(&wdeg[l], __uint_as_float(r.x));
    }
    __syncthreads();
    int v = cnt[tid];
    s[tid] = v;
    __syncthreads();
    for (int off = 1; off < 512; off <<= 1) {
        int t = s[tid];
        int add = (tid >= off) ? s[tid - off] : 0;
        __syncthreads();
        s[tid] = t + add;
        __syncthreads();
    }
    int excl = s[tid] - v;
    int node = nodeBase + tid;
    if (node < N_NODES) {
        rowptr[node] = bb + excl;
        dis[node] = rsqrtf(wdeg[tid] + 1.0f);   // +1 = self-loop weight
    }
    if (node == N_NODES) rowptr[N_NODES] = N_EDGES;
    cnt[tid] = excl;       // reuse as cursor
    __syncthreads();
    for (int e = tid; e < nEdge; e += 512) {
        uint2 r = tb[e];
        int l = (r.y >> 17) & 511;
        int p = atomicAdd(&cnt[l], 1);
        EdgeRec o;
        o.s = (int)(r.y & 0x1FFFFu);
        o.v = __uint_as_float(r.x);
        ed[bb + p] = o;
    }
}

// ---- MFMA matmul: h = bf16( dis[row] * (X @ W) ), K = 128 or 64 ----------
// 3-pass bf16 hi/lo split (Markidis): X = Xh + Xl, W = Wh + Wl;
// acc += Xh@Wh + Xh@Wl + Xl@Wh in fp32 MFMA accumulators. Residual error
// ~2^-17 relative -- far below the bf16 output quantization (2^-9) that
// already dominates absmax, so h is numerically identical to the fp32 path.
// Structure: 4 waves/block; wave w owns a 16-col block. B-fragments (hi+lo)
// are built ONCE per wave from global W and held in registers (16-32 VGPR).
// Grid-stride over 16-row tiles; A-fragments load straight from global X
// (32 B/lane, shared via L1 across the block's 4 waves) and split on the
// fly with v_cvt_pk_bf16_f32. No LDS. Epilogue identical to old mm kernels.
// mfma_f32_16x16x32_bf16 frag layout: A: lane l holds A[l&15][(l>>4)*8+j];
// B: lane l holds B[(l>>4)*8+j][l&15]; C/D: col=l&15, row=(l>>4)*4+reg.
template<int K>
__global__ __launch_bounds__(256) void mm_mfma(const float* __restrict__ X,
                                               const float* __restrict__ W,
                                               const float* __restrict__ dis,
                                               unsigned* __restrict__ h) {
    constexpr int NKS = K / 32;
    int wv = threadIdx.x >> 6;        // wave id = col-block 0..3
    int l  = threadIdx.x & 63;
    int lr = l & 15;                  // A-row / B-col within tile
    int kr = l >> 4;                  // k sub-block: k = ks*32 + kr*8 + j
    int col = wv * 16 + lr;
    // ---- B fragments (hi/lo), built once, live in registers ----
    F8 bhi[NKS], blo[NKS];
    #pragma unroll
    for (int ks = 0; ks < NKS; ++ks) {
        const float* wp = W + (ks * 32 + kr * 8) * 64 + col;
        float f[8];
        #pragma unroll
        for (int j = 0; j < 8; ++j) f[j] = wp[j * 64];
        split_frag(f, bhi[ks].u, blo[ks].u);
    }
    for (int t = blockIdx.x; t < N_NODES / 16; t += gridDim.x) {
        int row0 = t * 16;
        f32x4 acc = {0.f, 0.f, 0.f, 0.f};
        #pragma unroll
        for (int ks = 0; ks < NKS; ++ks) {
            const float4* xp = (const float4*)(X + (size_t)(row0 + lr) * K + ks * 32 + kr * 8);
            float4 fa = xp[0], fb = xp[1];
            float f[8] = {fa.x, fa.y, fa.z, fa.w, fb.x, fb.y, fb.z, fb.w};
            F8 ahi, alo;
            split_frag(f, ahi.u, alo.u);
            acc = __builtin_amdgcn_mfma_f32_16x16x32_bf16(ahi.f, bhi[ks].f, acc, 0, 0, 0);
            acc = __builtin_amdgcn_mfma_f32_16x16x32_bf16(ahi.f, blo[ks].f, acc, 0, 0, 0);
            acc = __builtin_amdgcn_mfma_f32_16x16x32_bf16(alo.f, bhi[ks].f, acc, 0, 0, 0);
        }
        int rbase = row0 + kr * 4;
        float v0 = acc[0] * dis[rbase + 0];
        float v1 = acc[1] * dis[rbase + 1];
        float v2 = acc[2] * dis[rbase + 2];
        float v3 = acc[3] * dis[rbase + 3];
        float o0 = __shfl_xor(v0, 1, 64);
        float o1 = __shfl_xor(v1, 1, 64);
        float o2 = __shfl_xor(v2, 1, 64);
        float o3 = __shfl_xor(v3, 1, 64);
        if ((lr & 1) == 0) {
            int ci = col >> 1;
            h[(rbase + 0) * 32 + ci] = pack_bf16(v0, o0);
            h[(rbase + 1) * 32 + ci] = pack_bf16(v1, o1);
            h[(rbase + 2) * 32 + ci] = pack_bf16(v2, o2);
            h[(rbase + 3) * 32 + ci] = pack_bf16(v3, o3);
        }
    }
}

// ---- CSR aggregate + fused epilogue (bf16 dis-scaled h rows, 128 B) ------
// one wave per node; 8 groups of 8 lanes; rows mask-padded to whole
// 32-edge batches (clamped index + zero weight); <=64 VGPR pinned.
__global__ __launch_bounds__(256, 8) void agg_kernel(const int* __restrict__ rowptr,
                                                     const EdgeRec* __restrict__ ed,
                                                     const unsigned* __restrict__ h,
                                                     const float* __restrict__ dis,
                                                     const float* __restrict__ b,
                                                     float* __restrict__ out,
                                                     int relu) {
    int node = blockIdx.x * 4 + (threadIdx.x >> 6);
    int lane = threadIdx.x & 63;
    int g = lane >> 3;        // edge group 0..7
    int cl = lane & 7;        // channel octet: channels 8*cl .. 8*cl+7
    int beg = rowptr[node];
    int end = rowptr[node + 1];
    const uint4* h16 = (const uint4*)h;                   // 8 uint4 per row
    const char*  hb  = (const char*)h + (size_t)cl * 16;  // lane's slice base
    float d  = dis[node];
    uint4 us = h16[(size_t)node * 8 + cl];
    f32x2 acc2[4];
    acc2[0] = 0.f; acc2[1] = 0.f; acc2[2] = 0.f; acc2[3] = 0.f;
    int n = end - beg;            // in-degree (excl self)
    int nb = (n + 31) >> 5;       // 32-edge batches, wave-uniform
    int nm1 = n - 1;
    uint2 q0, q1, q2, q3;
    if (nb > 0) {
        q0 = *(const uint2*)(ed + beg + min(g,      nm1));
        q1 = *(const uint2*)(ed + beg + min(g + 8,  nm1));
        q2 = *(const uint2*)(ed + beg + min(g + 16, nm1));
        q3 = *(const uint2*)(ed + beg + min(g + 24, nm1));
        for (int bt = 0; bt < nb; ++bt) {
            int ob = (bt << 5) + g;
            float w0 = (ob      < n) ? __uint_as_float(q0.y) : 0.f;
            float w1 = (ob + 8  < n) ? __uint_as_float(q1.y) : 0.f;
            float w2 = (ob + 16 < n) ? __uint_as_float(q2.y) : 0.f;
            float w3 = (ob + 24 < n) ? __uint_as_float(q3.y) : 0.f;
            uint4 u0 = *(const uint4*)(hb + ((size_t)(unsigned)q0.x << 7));
            uint4 u1 = *(const uint4*)(hb + ((size_t)(unsigned)q1.x << 7));
            uint4 u2 = *(const uint4*)(hb + ((size_t)(unsigned)q2.x << 7));
            uint4 u3 = *(const uint4*)(hb + ((size_t)(unsigned)q3.x << 7));
            if (bt + 1 < nb) {
                int on = ob + 32;
                q0 = *(const uint2*)(ed + beg + min(on,      nm1));
                q1 = *(const uint2*)(ed + beg + min(on + 8,  nm1));
                q2 = *(const uint2*)(ed + beg + min(on + 16, nm1));
                q3 = *(const uint2*)(ed + beg + min(on + 24, nm1));
            }
            edge_acc(acc2, u0, w0);
            edge_acc(acc2, u1, w1);
            edge_acc(acc2, u2, w2);
            edge_acc(acc2, u3, w3);
        }
    }
    float acc[8] = { acc2[0].x, acc2[0].y, acc2[1].x, acc2[1].y,
                     acc2[2].x, acc2[2].y, acc2[3].x, acc2[3].y };
    #pragma unroll
    for (int kk = 0; kk < 8; ++kk) {
        acc[kk] += __shfl_xor(acc[kk], 8, 64);
        acc[kk] += __shfl_xor(acc[kk], 16, 64);
        acc[kk] += __shfl_xor(acc[kk], 32, 64);
    }
    if (g == 0) {
        float hs[8] = { bf_lo(us.x), bf_hi(us.x), bf_lo(us.y), bf_hi(us.y),
                        bf_lo(us.z), bf_hi(us.z), bf_lo(us.w), bf_hi(us.w) };
        const float4* b4 = (const float4*)b;
        float4 bv0 = b4[cl * 2], bv1 = b4[cl * 2 + 1];
        float4 v0, v1;
        v0.x = d * (acc[0] + hs[0]) + bv0.x;
        v0.y = d * (acc[1] + hs[1]) + bv0.y;
        v0.z = d * (acc[2] + hs[2]) + bv0.z;
        v0.w = d * (acc[3] + hs[3]) + bv0.w;
        v1.x = d * (acc[4] + hs[4]) + bv1.x;
        v1.y = d * (acc[5] + hs[5]) + bv1.y;
        v1.z = d * (acc[6] + hs[6]) + bv1.z;
        v1.w = d * (acc[7] + hs[7]) + bv1.w;
        if (relu) {
            v0.x = fmaxf(v0.x, 0.f); v0.y = fmaxf(v0.y, 0.f);
            v0.z = fmaxf(v0.z, 0.f); v0.w = fmaxf(v0.w, 0.f);
            v1.x = fmaxf(v1.x, 0.f); v1.y = fmaxf(v1.y, 0.f);
            v1.z = fmaxf(v1.z, 0.f); v1.w = fmaxf(v1.w, 0.f);
        }
        float4* o4 = (float4*)out;
        o4[node * 16 + cl * 2]     = v0;
        o4[node * 16 + cl * 2 + 1] = v1;
    }
}

extern "C" void kernel_launch(void* const* d_in, const int* in_sizes, int n_in,
                              void* d_out, int out_size, void* d_ws, size_t ws_size,
                              hipStream_t stream) {
    const float* x  = (const float*)d_in[0];
    const int*   ei = (const int*)d_in[1];   // [2, E]: sources then targets
    const float* ew = (const float*)d_in[2];
    const float* W1 = (const float*)d_in[3];
    const float* b1 = (const float*)d_in[4];
    const float* W2 = (const float*)d_in[5];
    const float* b2 = (const float*)d_in[6];
    float* out = (float*)d_out;

    // workspace carve-up (256 B aligned). tmpPad (28.9 MB, padded buckets)
    // is dead after fine_sort; bf16 h (12.8 MB) + f32 a (25.6 MB) overlay it.
    char* p = (char*)d_ws;
    auto carve = [&](size_t bytes) { char* r = p; p += (bytes + 255) & ~(size_t)255; return r; };
    float*    dis     = (float*)carve(N_NODES * 4);
    int*      rowptr  = (int*)carve((N_NODES + 1) * 4);
    int*      start   = (int*)carve(257 * 4);
    int*      gcursor = (int*)carve(256 * 4);
    EdgeRec*  ed      = (EdgeRec*)carve((size_t)N_EDGES * 8);
    size_t    r2sz    = (size_t)NBUCKET * CAP * 8;                 // 28.9 MB
    size_t    hasz    = (size_t)N_NODES * 64 * 6;                  // 38.4 MB
    char*     r2      = carve(r2sz > hasz ? r2sz : hasz);
    uint2*    tmpPad  = (uint2*)r2;
    unsigned* h       = (unsigned*)r2;                             // 12.8 MB
    float*    a       = (float*)(r2 + (size_t)N_NODES * 64 * 2);   // 25.6 MB

    // --- CSR build: direct padded reservation, no pre-histogram ---
    hipMemsetAsync(gcursor, 0, 256 * sizeof(int), stream);
    scatter_coarse<<<SC_GRID, 256, 0, stream>>>(ei, ew, gcursor, tmpPad);
    bucket_scan<<<1, 256, 0, stream>>>(gcursor, start);
    fine_sort<<<NBUCKET, 512, 0, stream>>>(start, tmpPad, rowptr, dis, ed);

    // --- layer 1: h = bf16(dis.(x@W1)) ; a = relu(agg(h) + b1) ---
    mm_mfma<IN_C><<<1250, 256, 0, stream>>>(x, W1, dis, h);
    agg_kernel<<<N_NODES / 4, 256, 0, stream>>>(rowptr, ed, h, dis, b1, a, 1);

    // --- layer 2: h = bf16(dis.(a@W2)) ; out = agg(h) + b2 ---
    mm_mfma<HID_C><<<1250, 256, 0, stream>>>(a, W2, dis, h);
    agg_kernel<<<N_NODES / 4, 256, 0, stream>>>(rowptr, ed, h, dis, b2, out, 0);
}